// Round 1
// baseline (180.858 us; speedup 1.0000x reference)
//
#include <hip/hip_runtime.h>
#include <hip/hip_bf16.h>

// SegmentLinear: y = sum_c (sx_c*sw_c) * (qx_c @ qw_c^T), int8-exact path.
// N = K = O = 4096, CHUNKS = 4, cs = 1024.

constexpr int NDIM = 4096;
constexpr int TOTAL4 = (NDIM * NDIM) / 4;   // float4 count per matrix

typedef int i32x4 __attribute__((ext_vector_type(4)));

// ---------------------------------------------------------------- amax pass
__global__ __launch_bounds__(256) void amax_kernel(
    const float* __restrict__ x, const float* __restrict__ w,
    unsigned int* __restrict__ amax) {
  const int t = threadIdx.x;
  const int c = blockIdx.x & 3;  // grid stride (1024*256 float4) is a multiple
                                 // of K/4=1024 -> whole block stays in chunk c
  float mx = 0.f, mw = 0.f;
  const float4* x4 = (const float4*)x;
  const float4* w4 = (const float4*)w;
  const int stride = 1024 * 256;
  for (int i = blockIdx.x * 256 + t; i < TOTAL4; i += stride) {
    float4 v = x4[i];
    mx = fmaxf(mx, fmaxf(fmaxf(fabsf(v.x), fabsf(v.y)),
                         fmaxf(fabsf(v.z), fabsf(v.w))));
    float4 u = w4[i];
    mw = fmaxf(mw, fmaxf(fmaxf(fabsf(u.x), fabsf(u.y)),
                         fmaxf(fabsf(u.z), fabsf(u.w))));
  }
  __shared__ float r0[256], r1[256];
  r0[t] = mx; r1[t] = mw;
  __syncthreads();
  for (int off = 128; off; off >>= 1) {
    if (t < off) {
      r0[t] = fmaxf(r0[t], r0[t + off]);
      r1[t] = fmaxf(r1[t], r1[t + off]);
    }
    __syncthreads();
  }
  if (t == 0) {
    atomicMax(&amax[c],     __float_as_uint(r0[0]));  // non-neg floats: uint order == float order
    atomicMax(&amax[4 + c], __float_as_uint(r1[0]));
  }
}

// ------------------------------------------------------------- quantize pass
__device__ __forceinline__ signed char quant1(float v, float s) {
  float r = rintf(v / s);                       // round-half-even, IEEE div: matches numpy
  r = fminf(fmaxf(r, -127.f), 127.f);
  return (signed char)(int)r;
}

__global__ __launch_bounds__(256) void quant_kernel(
    const float* __restrict__ x, const float* __restrict__ w,
    const unsigned int* __restrict__ amax,
    signed char* __restrict__ qx, signed char* __restrict__ qw) {
  const int t = threadIdx.x;
  const int c = blockIdx.x & 3;
  const float sx = fmaxf(__uint_as_float(amax[c])     / 127.0f, 1e-8f);
  const float sw = fmaxf(__uint_as_float(amax[4 + c]) / 127.0f, 1e-8f);
  const float4* x4 = (const float4*)x;
  const float4* w4 = (const float4*)w;
  char4* qx4 = (char4*)qx;
  char4* qw4 = (char4*)qw;
  const int stride = 1024 * 256;
  for (int i = blockIdx.x * 256 + t; i < TOTAL4; i += stride) {
    float4 v = x4[i];
    char4 q;
    q.x = quant1(v.x, sx); q.y = quant1(v.y, sx);
    q.z = quant1(v.z, sx); q.w = quant1(v.w, sx);
    qx4[i] = q;
    float4 u = w4[i];
    char4 p;
    p.x = quant1(u.x, sw); p.y = quant1(u.y, sw);
    p.z = quant1(u.z, sw); p.w = quant1(u.w, sw);
    qw4[i] = p;
  }
}

// ------------------------------------------------------------------ i8 GEMM
__device__ __forceinline__ void async16(const void* g, void* l) {
  __builtin_amdgcn_global_load_lds(
      (const __attribute__((address_space(1))) void*)g,
      (__attribute__((address_space(3))) void*)l, 16, 0, 0);
}

// 128x128 tile, BK=64 int8 bytes. 256 threads = 4 waves (2x2), 64x64 out/wave.
// mfma_i32_16x16x64_i8: lane = r + 16*kg holds 16 consecutive k-bytes.
// LDS 16B-slot XOR swizzle (slot ^= row&3) applied on BOTH the pre-swizzled
// global source of global_load_lds (linear LDS dest) and the ds_read address.
__global__ __launch_bounds__(256, 2) void gemm_i8_kernel(
    const signed char* __restrict__ qx, const signed char* __restrict__ qw,
    const unsigned int* __restrict__ amax, float* __restrict__ out) {
  __shared__ __align__(128) signed char lds_a[128 * 64];
  __shared__ __align__(128) signed char lds_b[128 * 64];

  const int t = threadIdx.x;
  const int lane = t & 63;
  const int wave = t >> 6;
  const int brow = blockIdx.y * 128;
  const int bcol = blockIdx.x * 128;
  const int wr = wave >> 1;
  const int wc = wave & 1;

  // per-chunk combined scales (exactly as reference computes them)
  float scp[4];
#pragma unroll
  for (int c = 0; c < 4; ++c) {
    float sx = fmaxf(__uint_as_float(amax[c])     / 127.0f, 1e-8f);
    float sw = fmaxf(__uint_as_float(amax[4 + c]) / 127.0f, 1e-8f);
    scp[c] = sx * sw;
  }

  // staging: thread (wave,lane), issue i writes LDS bytes
  //   off = i*4096 + wave*1024 + lane*16  ->  row ar = off/64, slot = lane&3
  const int ar0 = wave * 16 + (lane >> 2);
  const int ar1 = ar0 + 64;
  const int sl = lane & 3;
  const signed char* gax0 = qx + (size_t)(brow + ar0) * NDIM + ((sl ^ (ar0 & 3)) << 4);
  const signed char* gax1 = qx + (size_t)(brow + ar1) * NDIM + ((sl ^ (ar1 & 3)) << 4);
  const signed char* gbx0 = qw + (size_t)(bcol + ar0) * NDIM + ((sl ^ (ar0 & 3)) << 4);
  const signed char* gbx1 = qw + (size_t)(bcol + ar1) * NDIM + ((sl ^ (ar1 & 3)) << 4);
  signed char* lba = &lds_a[wave * 1024];  // wave-uniform LDS base
  signed char* lbb = &lds_b[wave * 1024];

  // fragment reads: row = wtile + m*16 + (lane&15), k-slot kg = lane>>4
  const int ra = wr * 64 + (lane & 15);
  const int rb = wc * 64 + (lane & 15);
  const int kg = lane >> 4;
  const int offa = ra * 64 + ((kg ^ (ra & 3)) << 4);
  const int offb = rb * 64 + ((kg ^ (rb & 3)) << 4);

  i32x4 iacc[4][4];
  float facc[4][4][4];
#pragma unroll
  for (int m = 0; m < 4; ++m)
#pragma unroll
    for (int n = 0; n < 4; ++n) {
      iacc[m][n] = i32x4{0, 0, 0, 0};
#pragma unroll
      for (int j = 0; j < 4; ++j) facc[m][n][j] = 0.f;
    }

#pragma unroll
  for (int c = 0; c < 4; ++c) {       // full unroll: c is compile-time (scp[c])
#pragma unroll 1
    for (int s16 = 0; s16 < 16; ++s16) {
      const int kt = c * 1024 + s16 * 64;
      __syncthreads();                 // all waves done reading previous tile
      async16(gax0 + kt, lba);
      async16(gax1 + kt, lba + 4096);
      async16(gbx0 + kt, lbb);
      async16(gbx1 + kt, lbb + 4096);
      __syncthreads();                 // drains vmcnt(0): staged data visible

      i32x4 av[4], bv[4];
#pragma unroll
      for (int m = 0; m < 4; ++m)
        av[m] = *(const i32x4*)&lds_a[offa + m * 16 * 64];
#pragma unroll
      for (int n = 0; n < 4; ++n)
        bv[n] = *(const i32x4*)&lds_b[offb + n * 16 * 64];
#pragma unroll
      for (int m = 0; m < 4; ++m)
#pragma unroll
        for (int n = 0; n < 4; ++n)
          iacc[m][n] = __builtin_amdgcn_mfma_i32_16x16x64_i8(
              av[m], bv[n], iacc[m][n], 0, 0, 0);
    }
    // chunk boundary: fold int32 acc into fp32 with this chunk's scale
    const float s = scp[c];
#pragma unroll
    for (int m = 0; m < 4; ++m)
#pragma unroll
      for (int n = 0; n < 4; ++n) {
#pragma unroll
        for (int j = 0; j < 4; ++j) facc[m][n][j] += s * (float)iacc[m][n][j];
        iacc[m][n] = i32x4{0, 0, 0, 0};
      }
  }

  // C/D layout (16x16): col = lane&15, row = (lane>>4)*4 + j
  const int orow = brow + wr * 64 + (lane >> 4) * 4;
  const int ocol = bcol + wc * 64 + (lane & 15);
#pragma unroll
  for (int m = 0; m < 4; ++m)
#pragma unroll
    for (int n = 0; n < 4; ++n)
#pragma unroll
      for (int j = 0; j < 4; ++j)
        out[(size_t)(orow + m * 16 + j) * NDIM + (ocol + n * 16)] = facc[m][n][j];
}

// ---------------------------------------------------------------- launcher
extern "C" void kernel_launch(void* const* d_in, const int* in_sizes, int n_in,
                              void* d_out, int out_size, void* d_ws, size_t ws_size,
                              hipStream_t stream) {
  const float* x = (const float*)d_in[0];
  const float* w = (const float*)d_in[1];
  float* out = (float*)d_out;

  unsigned int* amax = (unsigned int*)d_ws;                 // 8 uints
  signed char* qx = (signed char*)d_ws + 256;               // 16 MiB
  signed char* qw = qx + (size_t)NDIM * NDIM;               // 16 MiB

  hipMemsetAsync(d_ws, 0, 256, stream);
  amax_kernel<<<1024, 256, 0, stream>>>(x, w, amax);
  quant_kernel<<<1024, 256, 0, stream>>>(x, w, amax, qx, qw);
  dim3 grid(NDIM / 128, NDIM / 128);
  gemm_i8_kernel<<<grid, 256, 0, stream>>>(qx, qw, amax, out);
}